// Round 2
// baseline (834.499 us; speedup 1.0000x reference)
//
#include <hip/hip_runtime.h>
#include <hip/hip_bf16.h>

#define IN_F   4096
#define OUT_F  4096
#define M_TOT  8192
#define BM     128
#define BN     128
#define BK     64
#define KPAD   8          // +16B per LDS row: breaks 144B-stride bank pattern
#define LDK    (BK + KPAD)

typedef short  short8  __attribute__((ext_vector_type(8)));
typedef float  floatx4 __attribute__((ext_vector_type(4)));

// fp32 -> bf16 round-to-nearest-even (inputs here are never NaN)
__device__ __forceinline__ unsigned short f2bf(float f) {
    union { float f; unsigned u; } v; v.f = f;
    unsigned r = v.u + 0x7FFFu + ((v.u >> 16) & 1u);
    return (unsigned short)(r >> 16);
}

__global__ __launch_bounds__(256, 2)
void gptq_gemm_kernel(const float* __restrict__ x,
                      const int*   __restrict__ qweight,
                      const int*   __restrict__ qzeros,
                      const float* __restrict__ scales,   // fp16 in reference, promoted to fp32 by harness
                      float* __restrict__ out)
{
    __shared__ unsigned short As[BM][LDK];   // A tile, [m][k] bf16 bits
    __shared__ unsigned short Bs[BN][LDK];   // B tile transposed, [n][k] bf16 bits

    const int tid  = threadIdx.x;
    const int lane = tid & 63;
    const int wave = tid >> 6;
    const int wm   = wave >> 1;        // 2x2 wave grid, each wave does 64x64
    const int wn   = wave & 1;
    const int l16  = lane & 15;
    const int quad = lane >> 4;

    const int n0 = blockIdx.x * BN;
    const int m0 = blockIdx.y * BM;

    floatx4 acc[4][4];
    #pragma unroll
    for (int i = 0; i < 4; ++i)
        #pragma unroll
        for (int j = 0; j < 4; ++j)
            acc[i][j] = (floatx4){0.f, 0.f, 0.f, 0.f};

    // ---- per-thread staging constants ----
    // A: each thread owns column-group kg (8 k's), rows r0, r0+32, r0+64, r0+96
    const int kgA = tid & 7;
    const int r0A = tid >> 3;
    // B: each thread owns output column bn (fixed), packed-rows pk0, pk0+2, +4, +6
    const int bn   = tid & 127;
    const int pk0  = tid >> 7;           // 0 or 1
    const int gcol = n0 + bn;

    const int KT = IN_F / BK;            // 64 k-tiles

    for (int kt = 0; kt < KT; ++kt) {
        // ---------- stage A: fp32 -> bf16 into LDS ----------
        {
            const float* srcbase = x + (size_t)(m0 + r0A) * IN_F + kt * BK + kgA * 8;
            #pragma unroll
            for (int it = 0; it < 4; ++it) {
                const float4* p = (const float4*)(srcbase + (size_t)it * 32 * IN_F);
                float4 f0 = p[0];
                float4 f1 = p[1];
                short8 v;
                v[0] = (short)f2bf(f0.x); v[1] = (short)f2bf(f0.y);
                v[2] = (short)f2bf(f0.z); v[3] = (short)f2bf(f0.w);
                v[4] = (short)f2bf(f1.x); v[5] = (short)f2bf(f1.y);
                v[6] = (short)f2bf(f1.z); v[7] = (short)f2bf(f1.w);
                *(short8*)&As[r0A + it * 32][kgA * 8] = v;
            }
        }
        // ---------- stage B: int4 dequant -> bf16, K-transposed ----------
        {
            const int g = (kt * BK) >> 7;   // quant group (BK=64 => tile within one group)
            const unsigned qz = (unsigned)qzeros[g * (OUT_F / 8) + (gcol >> 3)];
            const int   z = (int)((qz >> (4 * (gcol & 7))) & 15u);
            const float s = scales[g * OUT_F + gcol];
            #pragma unroll
            for (int it = 0; it < 4; ++it) {
                const int pk = pk0 + it * 2;
                const unsigned q = (unsigned)qweight[(kt * 8 + pk) * OUT_F + gcol];
                short8 v;
                #pragma unroll
                for (int j = 0; j < 8; ++j) {
                    const int wi = (int)((q >> (4 * j)) & 15u);
                    v[j] = (short)f2bf((float)(wi - z) * s);  // matches ref: (w-z)*s in fp32, RTE to bf16
                }
                *(short8*)&Bs[bn][pk * 8] = v;
            }
        }
        __syncthreads();

        // ---------- compute: 2 x (4x4) mfma_f32_16x16x32_bf16 ----------
        #pragma unroll
        for (int kk = 0; kk < 2; ++kk) {
            const int ko = kk * 32 + quad * 8;   // lane's k-offset (A/B operand: k = quad*8+j)
            short8 af[4], bfv[4];
            #pragma unroll
            for (int i = 0; i < 4; ++i)
                af[i] = *(const short8*)&As[wm * 64 + i * 16 + l16][ko];
            #pragma unroll
            for (int j = 0; j < 4; ++j)
                bfv[j] = *(const short8*)&Bs[wn * 64 + j * 16 + l16][ko];
            #pragma unroll
            for (int i = 0; i < 4; ++i)
                #pragma unroll
                for (int j = 0; j < 4; ++j)
                    acc[i][j] = __builtin_amdgcn_mfma_f32_16x16x32_bf16(af[i], bfv[j], acc[i][j], 0, 0, 0);
        }
        __syncthreads();
    }

    // ---------- epilogue: C/D layout col=lane&15, row=quad*4+reg ----------
    float* obase = out + (size_t)(m0 + wm * 64 + quad * 4) * OUT_F + n0 + wn * 64 + l16;
    #pragma unroll
    for (int i = 0; i < 4; ++i)
        #pragma unroll
        for (int j = 0; j < 4; ++j)
            #pragma unroll
            for (int r = 0; r < 4; ++r)
                obase[(size_t)(i * 16 + r) * OUT_F + j * 16] = acc[i][j][r];
}

extern "C" void kernel_launch(void* const* d_in, const int* in_sizes, int n_in,
                              void* d_out, int out_size, void* d_ws, size_t ws_size,
                              hipStream_t stream) {
    const float* x       = (const float*)d_in[0];
    const int*   qweight = (const int*)d_in[1];
    const int*   qzeros  = (const int*)d_in[2];
    const float* scales  = (const float*)d_in[3];
    float* out = (float*)d_out;

    dim3 grid(OUT_F / BN, M_TOT / BM);   // (32, 64)
    gptq_gemm_kernel<<<grid, dim3(256), 0, stream>>>(x, qweight, qzeros, scales, out);
}

// Round 3
// 539.907 us; speedup vs baseline: 1.5456x; 1.5456x over previous
//
#include <hip/hip_runtime.h>
#include <hip/hip_bf16.h>

#define IN_F   4096
#define OUT_F  4096
#define M_TOT  8192
#define BM     128
#define BN     128
#define BK     64

typedef short  short8  __attribute__((ext_vector_type(8)));
typedef float  floatx4 __attribute__((ext_vector_type(4)));

// fp32 -> bf16 round-to-nearest-even (inputs here are never NaN)
__device__ __forceinline__ unsigned short f2bf(float f) {
    union { float f; unsigned u; } v; v.f = f;
    unsigned r = v.u + 0x7FFFu + ((v.u >> 16) & 1u);
    return (unsigned short)(r >> 16);
}

__device__ __forceinline__ void load_lds16(const unsigned short* g, unsigned short* l) {
    __builtin_amdgcn_global_load_lds(
        (const __attribute__((address_space(1))) unsigned int*)g,
        (__attribute__((address_space(3))) unsigned int*)l, 16, 0, 0);
}

// ---------------- pass 1a: x fp32 -> bf16 ----------------
__global__ __launch_bounds__(256)
void convert_x_kernel(const float* __restrict__ x, unsigned short* __restrict__ xb) {
    size_t i = ((size_t)blockIdx.x * 256 + threadIdx.x) * 8;
    const float4* p = (const float4*)(x + i);
    float4 f0 = p[0], f1 = p[1];
    short8 v;
    v[0] = (short)f2bf(f0.x); v[1] = (short)f2bf(f0.y);
    v[2] = (short)f2bf(f0.z); v[3] = (short)f2bf(f0.w);
    v[4] = (short)f2bf(f1.x); v[5] = (short)f2bf(f1.y);
    v[6] = (short)f2bf(f1.z); v[7] = (short)f2bf(f1.w);
    *(short8*)(xb + i) = v;
}

// ---------------- pass 1b: int4 dequant -> Wt[n][k] bf16 (LDS transpose) ----------------
// block: 64 n x 16 k-packets (=128 k, exactly one quant group). grid (64, 32).
__global__ __launch_bounds__(256)
void dequant_w_kernel(const int* __restrict__ qw, const int* __restrict__ qz,
                      const float* __restrict__ sc, unsigned short* __restrict__ Wt) {
    __shared__ unsigned short T[64][136];   // 64 n x 128 k, +8 pad
    const int t   = threadIdx.x;
    const int n0  = blockIdx.x * 64;
    const int g   = blockIdx.y;             // group index == kp-tile (16 kp/group)
    const int kp0 = g * 16;

    const int kp_l = t >> 4;                // 0..15
    const int n_l  = (t & 15) * 4;          // 0,4,..,60
    int4 q4 = *(const int4*)&qw[(size_t)(kp0 + kp_l) * OUT_F + n0 + n_l];
    #pragma unroll
    for (int j = 0; j < 4; ++j) {
        const int n = n0 + n_l + j;
        const unsigned z4 = (unsigned)qz[g * (OUT_F / 8) + (n >> 3)];
        const int   z = (int)((z4 >> (4 * (n & 7))) & 15u);
        const float s = sc[g * OUT_F + n];
        const unsigned q = ((const unsigned*)&q4)[j];
        short8 v;
        #pragma unroll
        for (int jj = 0; jj < 8; ++jj) {
            const int wi = (int)((q >> (4 * jj)) & 15u);
            v[jj] = (short)f2bf((float)(wi - z) * s);   // ref: (w-z)*s fp32, RNE->bf16
        }
        *(short8*)&T[n_l + j][kp_l * 8] = v;
    }
    __syncthreads();
    #pragma unroll
    for (int it = 0; it < 4; ++it) {
        const int p = t + it * 256;         // packet id in 64x16 tile
        const int row = p >> 4, c = p & 15;
        short8 v = *(short8*)&T[row][c * 8];
        *(short8*)&Wt[(size_t)(n0 + row) * IN_F + (size_t)(kp0 + c) * 8] = v;
    }
}

// ---------------- pass 2: bf16 GEMM, global_load_lds + XOR-swizzled LDS ----------------
// slot s in [0,1024): holds global packet (r = s>>3, kg = (s&7)^(r&7)); packet = 8 bf16 = 16B
__global__ __launch_bounds__(256)
void gemm_kernel(const unsigned short* __restrict__ A,   // [M][K] bf16
                 const unsigned short* __restrict__ Bm,  // [N][K] bf16
                 float* __restrict__ out) {
    __shared__ unsigned short As[BM * BK];
    __shared__ unsigned short Bs[BN * BK];

    const int tid  = threadIdx.x;
    const int lane = tid & 63;
    const int wave = tid >> 6;
    const int wm   = wave >> 1;
    const int wn   = wave & 1;
    const int l16  = lane & 15;
    const int quad = lane >> 4;

    const int n0 = blockIdx.x * BN;
    const int m0 = blockIdx.y * BM;

    floatx4 acc[4][4];
    #pragma unroll
    for (int i = 0; i < 4; ++i)
        #pragma unroll
        for (int j = 0; j < 4; ++j)
            acc[i][j] = (floatx4){0.f, 0.f, 0.f, 0.f};

    for (int kt = 0; kt < IN_F / BK; ++kt) {
        const unsigned short* Ab = A  + (size_t)m0 * IN_F + kt * BK;
        const unsigned short* Bb = Bm + (size_t)n0 * IN_F + kt * BK;
        #pragma unroll
        for (int it = 0; it < 4; ++it) {
            const int slotbase = wave * 64 + it * 256;   // wave-uniform
            const int slot = slotbase + lane;
            const int r  = slot >> 3;
            const int kg = (slot & 7) ^ (r & 7);
            load_lds16(Ab + (size_t)r * IN_F + kg * 8, &As[slotbase * 8]);
            load_lds16(Bb + (size_t)r * IN_F + kg * 8, &Bs[slotbase * 8]);
        }
        __syncthreads();

        #pragma unroll
        for (int kk = 0; kk < 2; ++kk) {
            short8 af[4], bfv[4];
            #pragma unroll
            for (int i = 0; i < 4; ++i) {
                const int r = wm * 64 + i * 16 + l16;
                const int slot = r * 8 + ((quad + kk * 4) ^ (r & 7));
                af[i] = *(const short8*)&As[slot * 8];
            }
            #pragma unroll
            for (int j = 0; j < 4; ++j) {
                const int r = wn * 64 + j * 16 + l16;
                const int slot = r * 8 + ((quad + kk * 4) ^ (r & 7));
                bfv[j] = *(const short8*)&Bs[slot * 8];
            }
            #pragma unroll
            for (int i = 0; i < 4; ++i)
                #pragma unroll
                for (int j = 0; j < 4; ++j)
                    acc[i][j] = __builtin_amdgcn_mfma_f32_16x16x32_bf16(af[i], bfv[j], acc[i][j], 0, 0, 0);
        }
        __syncthreads();
    }

    // epilogue: C/D layout col=lane&15, row=quad*4+reg (verified R2)
    float* obase = out + (size_t)(m0 + wm * 64 + quad * 4) * OUT_F + n0 + wn * 64 + l16;
    #pragma unroll
    for (int i = 0; i < 4; ++i)
        #pragma unroll
        for (int j = 0; j < 4; ++j)
            #pragma unroll
            for (int r = 0; r < 4; ++r)
                obase[(size_t)(i * 16 + r) * OUT_F + j * 16] = acc[i][j][r];
}

// ---------------- fallback: R2 fused kernel (verified correct) ----------------
#define KPAD   8
#define LDK    (BK + KPAD)
__global__ __launch_bounds__(256, 2)
void gptq_gemm_fused(const float* __restrict__ x,
                     const int*   __restrict__ qweight,
                     const int*   __restrict__ qzeros,
                     const float* __restrict__ scales,
                     float* __restrict__ out)
{
    __shared__ unsigned short As[BM][LDK];
    __shared__ unsigned short Bs[BN][LDK];
    const int tid  = threadIdx.x;
    const int lane = tid & 63;
    const int wave = tid >> 6;
    const int wm   = wave >> 1;
    const int wn   = wave & 1;
    const int l16  = lane & 15;
    const int quad = lane >> 4;
    const int n0 = blockIdx.x * BN;
    const int m0 = blockIdx.y * BM;

    floatx4 acc[4][4];
    #pragma unroll
    for (int i = 0; i < 4; ++i)
        #pragma unroll
        for (int j = 0; j < 4; ++j)
            acc[i][j] = (floatx4){0.f, 0.f, 0.f, 0.f};

    const int kgA = tid & 7;
    const int r0A = tid >> 3;
    const int bn   = tid & 127;
    const int pk0  = tid >> 7;
    const int gcol = n0 + bn;

    for (int kt = 0; kt < IN_F / BK; ++kt) {
        {
            const float* srcbase = x + (size_t)(m0 + r0A) * IN_F + kt * BK + kgA * 8;
            #pragma unroll
            for (int it = 0; it < 4; ++it) {
                const float4* p = (const float4*)(srcbase + (size_t)it * 32 * IN_F);
                float4 f0 = p[0]; float4 f1 = p[1];
                short8 v;
                v[0] = (short)f2bf(f0.x); v[1] = (short)f2bf(f0.y);
                v[2] = (short)f2bf(f0.z); v[3] = (short)f2bf(f0.w);
                v[4] = (short)f2bf(f1.x); v[5] = (short)f2bf(f1.y);
                v[6] = (short)f2bf(f1.z); v[7] = (short)f2bf(f1.w);
                *(short8*)&As[r0A + it * 32][kgA * 8] = v;
            }
        }
        {
            const int g = (kt * BK) >> 7;
            const unsigned qzv = (unsigned)qzeros[g * (OUT_F / 8) + (gcol >> 3)];
            const int   z = (int)((qzv >> (4 * (gcol & 7))) & 15u);
            const float s = scales[g * OUT_F + gcol];
            #pragma unroll
            for (int it = 0; it < 4; ++it) {
                const int pk = pk0 + it * 2;
                const unsigned q = (unsigned)qweight[(size_t)(kt * 8 + pk) * OUT_F + gcol];
                short8 v;
                #pragma unroll
                for (int j = 0; j < 8; ++j) {
                    const int wi = (int)((q >> (4 * j)) & 15u);
                    v[j] = (short)f2bf((float)(wi - z) * s);
                }
                *(short8*)&Bs[bn][pk * 8] = v;
            }
        }
        __syncthreads();
        #pragma unroll
        for (int kk = 0; kk < 2; ++kk) {
            const int ko = kk * 32 + quad * 8;
            short8 af[4], bfv[4];
            #pragma unroll
            for (int i = 0; i < 4; ++i)
                af[i] = *(const short8*)&As[wm * 64 + i * 16 + l16][ko];
            #pragma unroll
            for (int j = 0; j < 4; ++j)
                bfv[j] = *(const short8*)&Bs[wn * 64 + j * 16 + l16][ko];
            #pragma unroll
            for (int i = 0; i < 4; ++i)
                #pragma unroll
                for (int j = 0; j < 4; ++j)
                    acc[i][j] = __builtin_amdgcn_mfma_f32_16x16x32_bf16(af[i], bfv[j], acc[i][j], 0, 0, 0);
        }
        __syncthreads();
    }
    float* obase = out + (size_t)(m0 + wm * 64 + quad * 4) * OUT_F + n0 + wn * 64 + l16;
    #pragma unroll
    for (int i = 0; i < 4; ++i)
        #pragma unroll
        for (int j = 0; j < 4; ++j)
            #pragma unroll
            for (int r = 0; r < 4; ++r)
                obase[(size_t)(i * 16 + r) * OUT_F + j * 16] = acc[i][j][r];
}

extern "C" void kernel_launch(void* const* d_in, const int* in_sizes, int n_in,
                              void* d_out, int out_size, void* d_ws, size_t ws_size,
                              hipStream_t stream) {
    const float* x       = (const float*)d_in[0];
    const int*   qweight = (const int*)d_in[1];
    const int*   qzeros  = (const int*)d_in[2];
    const float* scales  = (const float*)d_in[3];
    float* out = (float*)d_out;

    const size_t XB_BYTES = (size_t)M_TOT * IN_F * 2;   // 64 MB
    const size_t WT_BYTES = (size_t)OUT_F * IN_F * 2;   // 32 MB

    if (ws_size >= XB_BYTES + WT_BYTES) {
        unsigned short* xb = (unsigned short*)d_ws;
        unsigned short* Wt = (unsigned short*)((char*)d_ws + XB_BYTES);
        convert_x_kernel<<<(M_TOT * IN_F) / (8 * 256), 256, 0, stream>>>(x, xb);
        dequant_w_kernel<<<dim3(OUT_F / 64, IN_F / 128), 256, 0, stream>>>(qweight, qzeros, scales, Wt);
        gemm_kernel<<<dim3(OUT_F / BN, M_TOT / BM), 256, 0, stream>>>(xb, Wt, out);
    } else {
        gptq_gemm_fused<<<dim3(OUT_F / BN, M_TOT / BM), 256, 0, stream>>>(x, qweight, qzeros, scales, out);
    }
}

// Round 4
// 470.421 us; speedup vs baseline: 1.7739x; 1.1477x over previous
//
#include <hip/hip_runtime.h>
#include <hip/hip_bf16.h>

#define IN_F   4096
#define OUT_F  4096
#define M_TOT  8192
#define BM     128
#define BN     128
#define BK     64

typedef short  short8  __attribute__((ext_vector_type(8)));
typedef float  floatx4 __attribute__((ext_vector_type(4)));

// fp32 -> bf16 round-to-nearest-even (inputs here are never NaN)
__device__ __forceinline__ unsigned short f2bf(float f) {
    union { float f; unsigned u; } v; v.f = f;
    unsigned r = v.u + 0x7FFFu + ((v.u >> 16) & 1u);
    return (unsigned short)(r >> 16);
}

__device__ __forceinline__ void load_lds16(const unsigned short* g, unsigned short* l) {
    __builtin_amdgcn_global_load_lds(
        (const __attribute__((address_space(1))) unsigned int*)g,
        (__attribute__((address_space(3))) unsigned int*)l, 16, 0, 0);
}

// ---------------- pass 1 (fused): W dequant blocks [0,2048) + x convert blocks [2048,18432) ----------------
#define NDQ 2048    // dequant blocks: 64n x 1group each
__global__ __launch_bounds__(256)
void prep_kernel(const float* __restrict__ x, const int* __restrict__ qw,
                 const int* __restrict__ qz, const float* __restrict__ sc,
                 unsigned short* __restrict__ xb, unsigned short* __restrict__ Wt) {
    __shared__ unsigned short T[64][136];
    const int t = threadIdx.x;
    if (blockIdx.x < NDQ) {
        // ---- int4 dequant -> Wt[n][k] bf16 (LDS transpose), verified R3 ----
        const int n0  = (blockIdx.x & 63) * 64;
        const int g   = blockIdx.x >> 6;          // quant group, 0..31
        const int kp0 = g * 16;
        const int kp_l = t >> 4;
        const int n_l  = (t & 15) * 4;
        int4 q4 = *(const int4*)&qw[(size_t)(kp0 + kp_l) * OUT_F + n0 + n_l];
        #pragma unroll
        for (int j = 0; j < 4; ++j) {
            const int n = n0 + n_l + j;
            const unsigned z4 = (unsigned)qz[g * (OUT_F / 8) + (n >> 3)];
            const int   z = (int)((z4 >> (4 * (n & 7))) & 15u);
            const float s = sc[g * OUT_F + n];
            const unsigned q = ((const unsigned*)&q4)[j];
            short8 v;
            #pragma unroll
            for (int jj = 0; jj < 8; ++jj) {
                const int wi = (int)((q >> (4 * jj)) & 15u);
                v[jj] = (short)f2bf((float)(wi - z) * s);   // ref: (w-z)*s fp32, RNE->bf16
            }
            *(short8*)&T[n_l + j][kp_l * 8] = v;
        }
        __syncthreads();
        #pragma unroll
        for (int it = 0; it < 4; ++it) {
            const int p = t + it * 256;
            const int row = p >> 4, c = p & 15;
            short8 v = *(short8*)&T[row][c * 8];
            *(short8*)&Wt[(size_t)(n0 + row) * IN_F + (size_t)(kp0 + c) * 8] = v;
        }
    } else {
        // ---- x fp32 -> bf16, verified R3 ----
        size_t i = ((size_t)(blockIdx.x - NDQ) * 256 + t) * 8;
        const float4* p = (const float4*)(x + i);
        float4 f0 = p[0], f1 = p[1];
        short8 v;
        v[0] = (short)f2bf(f0.x); v[1] = (short)f2bf(f0.y);
        v[2] = (short)f2bf(f0.z); v[3] = (short)f2bf(f0.w);
        v[4] = (short)f2bf(f1.x); v[5] = (short)f2bf(f1.y);
        v[6] = (short)f2bf(f1.z); v[7] = (short)f2bf(f1.w);
        *(short8*)(xb + i) = v;
    }
}

// ---------------- pass 2: bf16 GEMM, global_load_lds + XOR swizzle + hoisted addressing ----------------
// slot s in [0,1024): global packet (r = s>>3, kg = (s&7)^(r&7)); packet = 8 bf16 = 16B
__global__ __launch_bounds__(256, 2)
void gemm_kernel(const unsigned short* __restrict__ A,   // [M][K] bf16
                 const unsigned short* __restrict__ Bm,  // [N][K] bf16
                 float* __restrict__ out) {
    __shared__ unsigned short As[BM * BK];
    __shared__ unsigned short Bs[BN * BK];

    const int tid  = threadIdx.x;
    const int lane = tid & 63;
    const int wave = tid >> 6;
    const int wm   = wave >> 1;
    const int wn   = wave & 1;
    const int l16  = lane & 15;
    const int quad = lane >> 4;

    const int n0 = blockIdx.x * BN;
    const int m0 = blockIdx.y * BM;

    floatx4 acc[4][4];
    #pragma unroll
    for (int i = 0; i < 4; ++i)
        #pragma unroll
        for (int j = 0; j < 4; ++j)
            acc[i][j] = (floatx4){0.f, 0.f, 0.f, 0.f};

    // ---- hoisted per-thread global staging pointers (strength-reduced: += BK per iter) ----
    const unsigned short* pa[4];
    const unsigned short* pb[4];
    #pragma unroll
    for (int it = 0; it < 4; ++it) {
        const int slot = wave * 64 + it * 256 + lane;
        const int r  = slot >> 3;
        const int kg = (slot & 7) ^ (r & 7);
        pa[it] = A  + (size_t)(m0 + r) * IN_F + kg * 8;
        pb[it] = Bm + (size_t)(n0 + r) * IN_F + kg * 8;
    }
    // ---- hoisted loop-invariant LDS fragment offsets (element index) ----
    int aoff[2][4], boff[2][4];
    #pragma unroll
    for (int kk = 0; kk < 2; ++kk)
        #pragma unroll
        for (int i = 0; i < 4; ++i) {
            const int ra = wm * 64 + i * 16 + l16;
            aoff[kk][i] = (ra * 8 + ((quad + kk * 4) ^ (ra & 7))) * 8;
            const int rb = wn * 64 + i * 16 + l16;
            boff[kk][i] = (rb * 8 + ((quad + kk * 4) ^ (rb & 7))) * 8;
        }

    for (int kt = 0; kt < IN_F / BK; ++kt) {
        #pragma unroll
        for (int it = 0; it < 4; ++it) {
            const int dst = (wave * 64 + it * 256) * 8;   // wave-uniform LDS base
            load_lds16(pa[it], &As[dst]);
            load_lds16(pb[it], &Bs[dst]);
            pa[it] += BK;
            pb[it] += BK;
        }
        __syncthreads();

        #pragma unroll
        for (int kk = 0; kk < 2; ++kk) {
            short8 af[4], bfv[4];
            #pragma unroll
            for (int i = 0; i < 4; ++i) {
                af[i]  = *(const short8*)&As[aoff[kk][i]];
                bfv[i] = *(const short8*)&Bs[boff[kk][i]];
            }
            #pragma unroll
            for (int i = 0; i < 4; ++i)
                #pragma unroll
                for (int j = 0; j < 4; ++j)
                    acc[i][j] = __builtin_amdgcn_mfma_f32_16x16x32_bf16(af[i], bfv[j], acc[i][j], 0, 0, 0);
        }
        __syncthreads();
    }

    // epilogue: C/D layout col=lane&15, row=quad*4+reg (verified R2/R3)
    float* obase = out + (size_t)(m0 + wm * 64 + quad * 4) * OUT_F + n0 + wn * 64 + l16;
    #pragma unroll
    for (int i = 0; i < 4; ++i)
        #pragma unroll
        for (int j = 0; j < 4; ++j)
            #pragma unroll
            for (int r = 0; r < 4; ++r)
                obase[(size_t)(i * 16 + r) * OUT_F + j * 16] = acc[i][j][r];
}

// ---------------- fallback: R2 fused kernel (verified correct) ----------------
#define KPAD   8
#define LDK    (BK + KPAD)
__global__ __launch_bounds__(256, 2)
void gptq_gemm_fused(const float* __restrict__ x,
                     const int*   __restrict__ qweight,
                     const int*   __restrict__ qzeros,
                     const float* __restrict__ scales,
                     float* __restrict__ out)
{
    __shared__ unsigned short As[BM][LDK];
    __shared__ unsigned short Bs[BN][LDK];
    const int tid  = threadIdx.x;
    const int lane = tid & 63;
    const int wave = tid >> 6;
    const int wm   = wave >> 1;
    const int wn   = wave & 1;
    const int l16  = lane & 15;
    const int quad = lane >> 4;
    const int n0 = blockIdx.x * BN;
    const int m0 = blockIdx.y * BM;

    floatx4 acc[4][4];
    #pragma unroll
    for (int i = 0; i < 4; ++i)
        #pragma unroll
        for (int j = 0; j < 4; ++j)
            acc[i][j] = (floatx4){0.f, 0.f, 0.f, 0.f};

    const int kgA = tid & 7;
    const int r0A = tid >> 3;
    const int bn   = tid & 127;
    const int pk0  = tid >> 7;
    const int gcol = n0 + bn;

    for (int kt = 0; kt < IN_F / BK; ++kt) {
        {
            const float* srcbase = x + (size_t)(m0 + r0A) * IN_F + kt * BK + kgA * 8;
            #pragma unroll
            for (int it = 0; it < 4; ++it) {
                const float4* p = (const float4*)(srcbase + (size_t)it * 32 * IN_F);
                float4 f0 = p[0]; float4 f1 = p[1];
                short8 v;
                v[0] = (short)f2bf(f0.x); v[1] = (short)f2bf(f0.y);
                v[2] = (short)f2bf(f0.z); v[3] = (short)f2bf(f0.w);
                v[4] = (short)f2bf(f1.x); v[5] = (short)f2bf(f1.y);
                v[6] = (short)f2bf(f1.z); v[7] = (short)f2bf(f1.w);
                *(short8*)&As[r0A + it * 32][kgA * 8] = v;
            }
        }
        {
            const int g = (kt * BK) >> 7;
            const unsigned qzv = (unsigned)qzeros[g * (OUT_F / 8) + (gcol >> 3)];
            const int   z = (int)((qzv >> (4 * (gcol & 7))) & 15u);
            const float s = scales[g * OUT_F + gcol];
            #pragma unroll
            for (int it = 0; it < 4; ++it) {
                const int pk = pk0 + it * 2;
                const unsigned q = (unsigned)qweight[(size_t)(kt * 8 + pk) * OUT_F + gcol];
                short8 v;
                #pragma unroll
                for (int j = 0; j < 8; ++j) {
                    const int wi = (int)((q >> (4 * j)) & 15u);
                    v[j] = (short)f2bf((float)(wi - z) * s);
                }
                *(short8*)&Bs[bn][pk * 8] = v;
            }
        }
        __syncthreads();
        #pragma unroll
        for (int kk = 0; kk < 2; ++kk) {
            const int ko = kk * 32 + quad * 8;
            short8 af[4], bfv[4];
            #pragma unroll
            for (int i = 0; i < 4; ++i)
                af[i] = *(const short8*)&As[wm * 64 + i * 16 + l16][ko];
            #pragma unroll
            for (int j = 0; j < 4; ++j)
                bfv[j] = *(const short8*)&Bs[wn * 64 + j * 16 + l16][ko];
            #pragma unroll
            for (int i = 0; i < 4; ++i)
                #pragma unroll
                for (int j = 0; j < 4; ++j)
                    acc[i][j] = __builtin_amdgcn_mfma_f32_16x16x32_bf16(af[i], bfv[j], acc[i][j], 0, 0, 0);
        }
        __syncthreads();
    }
    float* obase = out + (size_t)(m0 + wm * 64 + quad * 4) * OUT_F + n0 + wn * 64 + l16;
    #pragma unroll
    for (int i = 0; i < 4; ++i)
        #pragma unroll
        for (int j = 0; j < 4; ++j)
            #pragma unroll
            for (int r = 0; r < 4; ++r)
                obase[(size_t)(i * 16 + r) * OUT_F + j * 16] = acc[i][j][r];
}

extern "C" void kernel_launch(void* const* d_in, const int* in_sizes, int n_in,
                              void* d_out, int out_size, void* d_ws, size_t ws_size,
                              hipStream_t stream) {
    const float* x       = (const float*)d_in[0];
    const int*   qweight = (const int*)d_in[1];
    const int*   qzeros  = (const int*)d_in[2];
    const float* scales  = (const float*)d_in[3];
    float* out = (float*)d_out;

    const size_t XB_BYTES = (size_t)M_TOT * IN_F * 2;   // 64 MB
    const size_t WT_BYTES = (size_t)OUT_F * IN_F * 2;   // 32 MB

    if (ws_size >= XB_BYTES + WT_BYTES) {
        unsigned short* xb = (unsigned short*)d_ws;
        unsigned short* Wt = (unsigned short*)((char*)d_ws + XB_BYTES);
        prep_kernel<<<NDQ + (M_TOT * IN_F) / (8 * 256), 256, 0, stream>>>(x, qweight, qzeros, scales, xb, Wt);
        gemm_kernel<<<dim3(OUT_F / BN, M_TOT / BM), 256, 0, stream>>>(xb, Wt, out);
    } else {
        gptq_gemm_fused<<<dim3(OUT_F / BN, M_TOT / BM), 256, 0, stream>>>(x, qweight, qzeros, scales, out);
    }
}

// Round 6
// 458.993 us; speedup vs baseline: 1.8181x; 1.0249x over previous
//
#include <hip/hip_runtime.h>
#include <hip/hip_bf16.h>

#define IN_F   4096
#define OUT_F  4096
#define M_TOT  8192
#define BM     128
#define BN     128
#define BK     64

typedef short  short8  __attribute__((ext_vector_type(8)));
typedef float  floatx4 __attribute__((ext_vector_type(4)));

// fp32 -> bf16 round-to-nearest-even (inputs here are never NaN)
__device__ __forceinline__ unsigned short f2bf(float f) {
    union { float f; unsigned u; } v; v.f = f;
    unsigned r = v.u + 0x7FFFu + ((v.u >> 16) & 1u);
    return (unsigned short)(r >> 16);
}

__device__ __forceinline__ void load_lds16(const unsigned short* g, unsigned short* l) {
    __builtin_amdgcn_global_load_lds(
        (const __attribute__((address_space(1))) unsigned int*)g,
        (__attribute__((address_space(3))) unsigned int*)l, 16, 0, 0);
}

// ---------------- pass 1 (fused): W dequant blocks [0,2048) + x convert blocks [2048,18432) ----------------
#define NDQ 2048    // dequant blocks: 64n x 1group each
__global__ __launch_bounds__(256)
void prep_kernel(const float* __restrict__ x, const int* __restrict__ qw,
                 const int* __restrict__ qz, const float* __restrict__ sc,
                 unsigned short* __restrict__ xb, unsigned short* __restrict__ Wt) {
    __shared__ unsigned short T[64][136];
    const int t = threadIdx.x;
    if (blockIdx.x < NDQ) {
        // ---- int4 dequant -> Wt[n][k] bf16 (LDS transpose), verified R3/R4 ----
        const int n0  = (blockIdx.x & 63) * 64;
        const int g   = blockIdx.x >> 6;          // quant group, 0..31
        const int kp0 = g * 16;
        const int kp_l = t >> 4;
        const int n_l  = (t & 15) * 4;
        int4 q4 = *(const int4*)&qw[(size_t)(kp0 + kp_l) * OUT_F + n0 + n_l];
        #pragma unroll
        for (int j = 0; j < 4; ++j) {
            const int n = n0 + n_l + j;
            const unsigned z4 = (unsigned)qz[g * (OUT_F / 8) + (n >> 3)];
            const int   z = (int)((z4 >> (4 * (n & 7))) & 15u);
            const float s = sc[g * OUT_F + n];
            const unsigned q = ((const unsigned*)&q4)[j];
            short8 v;
            #pragma unroll
            for (int jj = 0; jj < 8; ++jj) {
                const int wi = (int)((q >> (4 * jj)) & 15u);
                v[jj] = (short)f2bf((float)(wi - z) * s);   // ref: (w-z)*s fp32, RNE->bf16
            }
            *(short8*)&T[n_l + j][kp_l * 8] = v;
        }
        __syncthreads();
        #pragma unroll
        for (int it = 0; it < 4; ++it) {
            const int p = t + it * 256;
            const int row = p >> 4, c = p & 15;
            short8 v = *(short8*)&T[row][c * 8];
            *(short8*)&Wt[(size_t)(n0 + row) * IN_F + (size_t)(kp0 + c) * 8] = v;
        }
    } else {
        // ---- x fp32 -> bf16, verified R3/R4 ----
        size_t i = ((size_t)(blockIdx.x - NDQ) * 256 + t) * 8;
        const float4* p = (const float4*)(x + i);
        float4 f0 = p[0], f1 = p[1];
        short8 v;
        v[0] = (short)f2bf(f0.x); v[1] = (short)f2bf(f0.y);
        v[2] = (short)f2bf(f0.z); v[3] = (short)f2bf(f0.w);
        v[4] = (short)f2bf(f1.x); v[5] = (short)f2bf(f1.y);
        v[6] = (short)f2bf(f1.z); v[7] = (short)f2bf(f1.w);
        *(short8*)(xb + i) = v;
    }
}

// ---------------- pass 2: bf16 GEMM (R4-verified) + nontemporal epilogue stores ----------------
// slot s in [0,1024): global packet (r = s>>3, kg = (s&7)^(r&7)); packet = 8 bf16 = 16B
__global__ __launch_bounds__(256, 2)
void gemm_kernel(const unsigned short* __restrict__ A,   // [M][K] bf16
                 const unsigned short* __restrict__ Bm,  // [N][K] bf16
                 float* __restrict__ out) {
    __shared__ unsigned short As[BM * BK];
    __shared__ unsigned short Bs[BN * BK];

    const int tid  = threadIdx.x;
    const int lane = tid & 63;
    const int wave = tid >> 6;
    const int wm   = wave >> 1;
    const int wn   = wave & 1;
    const int l16  = lane & 15;
    const int quad = lane >> 4;

    const int n0 = blockIdx.x * BN;
    const int m0 = blockIdx.y * BM;

    floatx4 acc[4][4];
    #pragma unroll
    for (int i = 0; i < 4; ++i)
        #pragma unroll
        for (int j = 0; j < 4; ++j)
            acc[i][j] = (floatx4){0.f, 0.f, 0.f, 0.f};

    // ---- hoisted per-thread global staging pointers (+= BK per iter) ----
    const unsigned short* pa[4];
    const unsigned short* pb[4];
    #pragma unroll
    for (int it = 0; it < 4; ++it) {
        const int slot = wave * 64 + it * 256 + lane;
        const int r  = slot >> 3;
        const int kg = (slot & 7) ^ (r & 7);
        pa[it] = A  + (size_t)(m0 + r) * IN_F + kg * 8;
        pb[it] = Bm + (size_t)(n0 + r) * IN_F + kg * 8;
    }
    // ---- hoisted loop-invariant LDS fragment offsets (element index) ----
    int aoff[2][4], boff[2][4];
    #pragma unroll
    for (int kk = 0; kk < 2; ++kk)
        #pragma unroll
        for (int i = 0; i < 4; ++i) {
            const int ra = wm * 64 + i * 16 + l16;
            aoff[kk][i] = (ra * 8 + ((quad + kk * 4) ^ (ra & 7))) * 8;
            const int rb = wn * 64 + i * 16 + l16;
            boff[kk][i] = (rb * 8 + ((quad + kk * 4) ^ (rb & 7))) * 8;
        }

    for (int kt = 0; kt < IN_F / BK; ++kt) {
        #pragma unroll
        for (int it = 0; it < 4; ++it) {
            const int dst = (wave * 64 + it * 256) * 8;   // wave-uniform LDS base
            load_lds16(pa[it], &As[dst]);
            load_lds16(pb[it], &Bs[dst]);
            pa[it] += BK;
            pb[it] += BK;
        }
        __syncthreads();

        #pragma unroll
        for (int kk = 0; kk < 2; ++kk) {
            short8 af[4], bfv[4];
            #pragma unroll
            for (int i = 0; i < 4; ++i) {
                af[i]  = *(const short8*)&As[aoff[kk][i]];
                bfv[i] = *(const short8*)&Bs[boff[kk][i]];
            }
            #pragma unroll
            for (int i = 0; i < 4; ++i)
                #pragma unroll
                for (int j = 0; j < 4; ++j)
                    acc[i][j] = __builtin_amdgcn_mfma_f32_16x16x32_bf16(af[i], bfv[j], acc[i][j], 0, 0, 0);
        }
        __syncthreads();
    }

    // epilogue: C/D layout col=lane&15, row=quad*4+reg (verified R2-R4); NT stores to spare L2
    float* obase = out + (size_t)(m0 + wm * 64 + quad * 4) * OUT_F + n0 + wn * 64 + l16;
    #pragma unroll
    for (int i = 0; i < 4; ++i)
        #pragma unroll
        for (int j = 0; j < 4; ++j)
            #pragma unroll
            for (int r = 0; r < 4; ++r)
                __builtin_nontemporal_store(acc[i][j][r],
                    &obase[(size_t)(i * 16 + r) * OUT_F + j * 16]);
}

// ---------------- fallback: R2 fused kernel (verified correct) ----------------
#define KPAD   8
#define LDK    (BK + KPAD)
__global__ __launch_bounds__(256, 2)
void gptq_gemm_fused(const float* __restrict__ x,
                     const int*   __restrict__ qweight,
                     const int*   __restrict__ qzeros,
                     const float* __restrict__ scales,
                     float* __restrict__ out)
{
    __shared__ unsigned short As[BM][LDK];
    __shared__ unsigned short Bs[BN][LDK];
    const int tid  = threadIdx.x;
    const int lane = tid & 63;
    const int wave = tid >> 6;
    const int wm   = wave >> 1;
    const int wn   = wave & 1;
    const int l16  = lane & 15;
    const int quad = lane >> 4;
    const int n0 = blockIdx.x * BN;
    const int m0 = blockIdx.y * BM;

    floatx4 acc[4][4];
    #pragma unroll
    for (int i = 0; i < 4; ++i)
        #pragma unroll
        for (int j = 0; j < 4; ++j)
            acc[i][j] = (floatx4){0.f, 0.f, 0.f, 0.f};

    const int kgA = tid & 7;
    const int r0A = tid >> 3;
    const int bn   = tid & 127;
    const int pk0  = tid >> 7;
    const int gcol = n0 + bn;

    for (int kt = 0; kt < IN_F / BK; ++kt) {
        {
            const float* srcbase = x + (size_t)(m0 + r0A) * IN_F + kt * BK + kgA * 8;
            #pragma unroll
            for (int it = 0; it < 4; ++it) {
                const float4* p = (const float4*)(srcbase + (size_t)it * 32 * IN_F);
                float4 f0 = p[0]; float4 f1 = p[1];
                short8 v;
                v[0] = (short)f2bf(f0.x); v[1] = (short)f2bf(f0.y);
                v[2] = (short)f2bf(f0.z); v[3] = (short)f2bf(f0.w);
                v[4] = (short)f2bf(f1.x); v[5] = (short)f2bf(f1.y);
                v[6] = (short)f2bf(f1.z); v[7] = (short)f2bf(f1.w);
                *(short8*)&As[r0A + it * 32][kgA * 8] = v;
            }
        }
        {
            const int g = (kt * BK) >> 7;
            const unsigned qzv = (unsigned)qzeros[g * (OUT_F / 8) + (gcol >> 3)];
            const int   z = (int)((qzv >> (4 * (gcol & 7))) & 15u);
            const float s = scales[g * OUT_F + gcol];
            #pragma unroll
            for (int it = 0; it < 4; ++it) {
                const int pk = pk0 + it * 2;
                const unsigned q = (unsigned)qweight[(size_t)(kt * 8 + pk) * OUT_F + gcol];
                short8 v;
                #pragma unroll
                for (int j = 0; j < 8; ++j) {
                    const int wi = (int)((q >> (4 * j)) & 15u);
                    v[j] = (short)f2bf((float)(wi - z) * s);
                }
                *(short8*)&Bs[bn][pk * 8] = v;
            }
        }
        __syncthreads();
        #pragma unroll
        for (int kk = 0; kk < 2; ++kk) {
            const int ko = kk * 32 + quad * 8;
            short8 af[4], bfv[4];
            #pragma unroll
            for (int i = 0; i < 4; ++i)
                af[i] = *(const short8*)&As[wm * 64 + i * 16 + l16][ko];
            #pragma unroll
            for (int j = 0; j < 4; ++j)
                bfv[j] = *(const short8*)&Bs[wn * 64 + j * 16 + l16][ko];
            #pragma unroll
            for (int i = 0; i < 4; ++i)
                #pragma unroll
                for (int j = 0; j < 4; ++j)
                    acc[i][j] = __builtin_amdgcn_mfma_f32_16x16x32_bf16(af[i], bfv[j], acc[i][j], 0, 0, 0);
        }
        __syncthreads();
    }
    float* obase = out + (size_t)(m0 + wm * 64 + quad * 4) * OUT_F + n0 + wn * 64 + l16;
    #pragma unroll
    for (int i = 0; i < 4; ++i)
        #pragma unroll
        for (int j = 0; j < 4; ++j)
            #pragma unroll
            for (int r = 0; r < 4; ++r)
                obase[(size_t)(i * 16 + r) * OUT_F + j * 16] = acc[i][j][r];
}

extern "C" void kernel_launch(void* const* d_in, const int* in_sizes, int n_in,
                              void* d_out, int out_size, void* d_ws, size_t ws_size,
                              hipStream_t stream) {
    const float* x       = (const float*)d_in[0];
    const int*   qweight = (const int*)d_in[1];
    const int*   qzeros  = (const int*)d_in[2];
    const float* scales  = (const float*)d_in[3];
    float* out = (float*)d_out;

    const size_t XB_BYTES = (size_t)M_TOT * IN_F * 2;   // 64 MB
    const size_t WT_BYTES = (size_t)OUT_F * IN_F * 2;   // 32 MB

    if (ws_size >= XB_BYTES + WT_BYTES) {
        unsigned short* xb = (unsigned short*)d_ws;
        unsigned short* Wt = (unsigned short*)((char*)d_ws + XB_BYTES);
        prep_kernel<<<NDQ + (M_TOT * IN_F) / (8 * 256), 256, 0, stream>>>(x, qweight, qzeros, scales, xb, Wt);
        gemm_kernel<<<dim3(OUT_F / BN, M_TOT / BM), 256, 0, stream>>>(xb, Wt, out);
    } else {
        gptq_gemm_fused<<<dim3(OUT_F / BN, M_TOT / BM), 256, 0, stream>>>(x, qweight, qzeros, scales, out);
    }
}